// Round 10
// baseline (16173.120 us; speedup 1.0000x reference)
//
#include <hip/hip_runtime.h>
#include <hip/hip_bf16.h>
#include <stdint.h>

#define UNITS 400
#define GATES 1600
#define TLEN  1000
#define BATCH 64

#define NBLK 25        // blocks per group (16 units each)
#define NGRP 8         // groups; blockIdx = j*NGRP+gr -> group is XCD-local
#define BPG  8         // batches per group
#define UPB  16        // units per block
#define CPB  64        // cols per block
#define KK   20        // k-split (z-threads = KK*16 = 320)
#define KCH  20        // k per z-thread
#define WST  66        // wsh row stride in floats (bank-spread)
#define ZBS  65        // zpart batch stride (floats)
#define ZKS  (BPG*ZBS) // 520: zpart kk stride

// d_ws layout
#define WBUF_OFF 0
#define WBUF_SZ  (NBLK*UNITS*CPB*4)      // 2,560,000
#define HBUF_OFF (WBUF_OFF + WBUF_SZ)
#define HBUF_SZ  (2*UNITS*BATCH*8)       //   409,600 (u64 packets, [p][u][b])
#define WS_FULL  ((size_t)(HBUF_OFF + HBUF_SZ))

__device__ __forceinline__ float sigmoid_(float x) {
    return 1.0f / (1.0f + __expf(-x));
}
__device__ __forceinline__ float tanh_(float x) {
    return 1.0f - 2.0f / (__expf(2.0f * x) + 1.0f);
}

// ---- one-time reorder: wbuf[j][k][c] = W_h[k][(c/16)*400 + j*16 + c%16] ----
__global__ void reorder_w(const float* __restrict__ W_h, float* __restrict__ wbuf) {
    int i = blockIdx.x * 256 + threadIdx.x;
    if (i >= NBLK * UNITS * CPB) return;
    int c = i % CPB;
    int k = (i / CPB) % UNITS;
    int j = i / (CPB * UNITS);
    int col = (c / UPB) * UNITS + j * UPB + (c % UPB);
    wbuf[i] = W_h[k * GATES + col];
}

__global__ __launch_bounds__(512, 1) void lstm_mb(
    const float* __restrict__ x,      // [B,T,3]
    const float* __restrict__ W_x,    // [3,1600]
    const float* __restrict__ bvec,   // [1600]
    const float* __restrict__ p_i,
    const float* __restrict__ p_f,
    const float* __restrict__ p_o,
    const float* __restrict__ W_out,  // [400,3]
    const float* __restrict__ b_out,  // [3]
    const float* __restrict__ wbuf,
    unsigned long long* __restrict__ hbuf,   // [2][U][B] {tag,val}
    float* __restrict__ out)                 // [B,T,3]
{
    const int gr  = blockIdx.x % NGRP;   // all 25 blocks of a group share an XCD
    const int j   = blockIdx.x / NGRP;
    const int tid = threadIdx.x;

    __shared__ float wsh[UNITS * WST];       // 105,600 B  weight slice (LDS-resident)
    __shared__ float zpart[KK * ZKS];        //  41,600 B  k-partials
    __shared__ float hsh[BPG][UNITS];        //  12,800 B
    __shared__ float xsh[BPG][4];
    __shared__ float yred[3][4];

    // ---- load weight slice into LDS once (coalesced, conflict-light) ----
    {
        const float* wslice = wbuf + (size_t)j * UNITS * CPB;
        for (int i = tid; i < UNITS * CPB; i += 512)
            wsh[(i >> 6) * WST + (i & 63)] = wslice[i];
    }

    // ---- roles ----
    const int  kk = tid >> 4, cq = tid & 15;     // z-role: tid < 320
    const bool zrole = (tid < KK * UPB);
    const int  k0 = kk * KCH;

    const int  gb = tid >> 4, gu = tid & 15;     // gate-role: tid < 128
    const bool grole = (tid < BPG * UPB);

    // ---- gate-thread hoists ----
    int unit = 0, batch = 0;
    float wxr[3][4], bbv[4];
    float piu = 0.f, pfu = 0.f, pou = 0.f, cc = 0.f;
    if (grole) {
        unit  = j * UPB + gu;
        batch = gr * BPG + gb;
        #pragma unroll
        for (int g = 0; g < 4; ++g) {
            const int gcol = g * UNITS + unit;
            wxr[0][g] = W_x[gcol];
            wxr[1][g] = W_x[GATES + gcol];
            wxr[2][g] = W_x[2 * GATES + gcol];
            bbv[g]    = bvec[gcol];
        }
        piu = p_i[unit]; pfu = p_f[unit]; pou = p_o[unit];
    }
    if (tid < UNITS) {
        #pragma unroll
        for (int b = 0; b < BPG; ++b) hsh[b][tid] = 0.f;
    }
    __syncthreads();

#define FMA4(A, s, W) \
    A.x = fmaf(s, W.x, A.x); A.y = fmaf(s, W.y, A.y); \
    A.z = fmaf(s, W.z, A.z); A.w = fmaf(s, W.w, A.w);

    for (int t = 0; t < TLEN; ++t) {
        const int p = t & 1;

        // ================= A: z-partials / y(t-1) partials / x stage ============
        if (zrole) {
            float4 A0 = {0,0,0,0}, A1 = A0, A2 = A0, A3 = A0,
                   A4 = A0, A5 = A0, A6 = A0, A7 = A0;
            #pragma unroll
            for (int ko = 0; ko < KCH; ko += 4) {
                const float* wp = &wsh[(k0 + ko) * WST + (cq << 2)];
                const float4 w0 = *(const float4*)(wp);
                const float4 w1 = *(const float4*)(wp + WST);
                const float4 w2 = *(const float4*)(wp + 2 * WST);
                const float4 w3 = *(const float4*)(wp + 3 * WST);
#define BDO(B, AB) { const float4 hb = *(const float4*)&hsh[B][k0 + ko]; \
                     FMA4(AB, hb.x, w0) FMA4(AB, hb.y, w1)               \
                     FMA4(AB, hb.z, w2) FMA4(AB, hb.w, w3) }
                BDO(0, A0) BDO(1, A1) BDO(2, A2) BDO(3, A3)
                BDO(4, A4) BDO(5, A5) BDO(6, A6) BDO(7, A7)
#undef BDO
            }
            const int zb = kk * ZKS + (cq << 2);
            *(float4*)&zpart[zb + 0 * ZBS] = A0;
            *(float4*)&zpart[zb + 1 * ZBS] = A1;
            *(float4*)&zpart[zb + 2 * ZBS] = A2;
            *(float4*)&zpart[zb + 3 * ZBS] = A3;
            *(float4*)&zpart[zb + 4 * ZBS] = A4;
            *(float4*)&zpart[zb + 5 * ZBS] = A5;
            *(float4*)&zpart[zb + 6 * ZBS] = A6;
            *(float4*)&zpart[zb + 7 * ZBS] = A7;
        } else if (tid >= 320 && tid < 332) {
            if (j < BPG && t > 0) {
                // y partial for step t-1 (hsh holds that step's output h)
                const int f = (tid - 320) >> 2, ch = (tid - 320) & 3;
                float s = 0.f;
                const int u0 = ch * 100;
                #pragma unroll 4
                for (int u = u0; u < u0 + 100; ++u)
                    s += hsh[j][u] * W_out[u * 3 + f];
                yred[f][ch] = s;
            }
        } else if (tid >= 332 && tid < 332 + BPG * 3) {
            const int b = (tid - 332) / 3, f = (tid - 332) % 3;
            xsh[b][f] = x[((size_t)(gr * BPG + b) * TLEN + t) * 3 + f];
        }
        __syncthreads();   // zpart/xsh/yred ready; hsh reads done

        // ================= B: gates + publish  ∥  C: y-write + poll =============
        if (grole) {
            const float x0 = xsh[gb][0], x1 = xsh[gb][1], x2 = xsh[gb][2];
            float s[4];
            #pragma unroll
            for (int g = 0; g < 4; ++g) {
                float acc = fmaf(x0, wxr[0][g],
                            fmaf(x1, wxr[1][g],
                            fmaf(x2, wxr[2][g], bbv[g])));
                const int base = gb * ZBS + g * UPB + gu;
                #pragma unroll
                for (int q = 0; q < KK; ++q) acc += zpart[q * ZKS + base];
                s[g] = acc;
            }
            const float ig = sigmoid_(fmaf(piu, cc, s[0]));
            const float fg = sigmoid_(fmaf(pfu, cc, s[1]));
            const float gg = tanh_(s[2]);
            const float cn = fmaf(fg, cc, ig * gg);
            const float og = sigmoid_(fmaf(pou, cn, s[3]));
            const float hn = og * tanh_(cn);
            cc = cn;
            hsh[gb][unit] = hn;   // own slice locally
            const unsigned long long pkt =
                ((unsigned long long)(unsigned)(t + 1) << 32) |
                (unsigned long long)__float_as_uint(hn);
            __hip_atomic_store(&hbuf[(size_t)p * UNITS * BATCH + (size_t)unit * BATCH + batch],
                               pkt, __ATOMIC_RELAXED, __HIP_MEMORY_SCOPE_AGENT);
        } else {
            // y final write for t-1 (3 threads; before entering the poll)
            if (t > 0 && j < BPG && tid < 131) {
                const int f = tid - 128;
                out[((size_t)(gr * BPG + j) * TLEN + (t - 1)) * 3 + f] =
                    b_out[f] + yred[f][0] + yred[f][1] + yred[f][2] + yred[f][3];
            }
            // poll: one remote unit (skip own block's 16), all 8 batches = 64B line
            const int idx = tid - 128;                 // 0..383
            const int pu  = idx + (idx >= j * UPB ? UPB : 0);
            const unsigned want = (unsigned)(t + 1);
            const size_t base = (size_t)p * UNITS * BATCH + (size_t)pu * BATCH + gr * BPG;
            unsigned long long v0, v1, v2, v3, v4, v5, v6, v7;
            for (;;) {
                v0 = __hip_atomic_load(&hbuf[base + 0], __ATOMIC_RELAXED, __HIP_MEMORY_SCOPE_AGENT);
                v1 = __hip_atomic_load(&hbuf[base + 1], __ATOMIC_RELAXED, __HIP_MEMORY_SCOPE_AGENT);
                v2 = __hip_atomic_load(&hbuf[base + 2], __ATOMIC_RELAXED, __HIP_MEMORY_SCOPE_AGENT);
                v3 = __hip_atomic_load(&hbuf[base + 3], __ATOMIC_RELAXED, __HIP_MEMORY_SCOPE_AGENT);
                v4 = __hip_atomic_load(&hbuf[base + 4], __ATOMIC_RELAXED, __HIP_MEMORY_SCOPE_AGENT);
                v5 = __hip_atomic_load(&hbuf[base + 5], __ATOMIC_RELAXED, __HIP_MEMORY_SCOPE_AGENT);
                v6 = __hip_atomic_load(&hbuf[base + 6], __ATOMIC_RELAXED, __HIP_MEMORY_SCOPE_AGENT);
                v7 = __hip_atomic_load(&hbuf[base + 7], __ATOMIC_RELAXED, __HIP_MEMORY_SCOPE_AGENT);
                const unsigned ok =
                    ((unsigned)(v0 >> 32) == want) & ((unsigned)(v1 >> 32) == want) &
                    ((unsigned)(v2 >> 32) == want) & ((unsigned)(v3 >> 32) == want) &
                    ((unsigned)(v4 >> 32) == want) & ((unsigned)(v5 >> 32) == want) &
                    ((unsigned)(v6 >> 32) == want) & ((unsigned)(v7 >> 32) == want);
                if (ok) break;
                __builtin_amdgcn_s_sleep(2);
            }
            hsh[0][pu] = __uint_as_float((unsigned)v0);
            hsh[1][pu] = __uint_as_float((unsigned)v1);
            hsh[2][pu] = __uint_as_float((unsigned)v2);
            hsh[3][pu] = __uint_as_float((unsigned)v3);
            hsh[4][pu] = __uint_as_float((unsigned)v4);
            hsh[5][pu] = __uint_as_float((unsigned)v5);
            hsh[6][pu] = __uint_as_float((unsigned)v6);
            hsh[7][pu] = __uint_as_float((unsigned)v7);
        }
        __syncthreads();   // hsh = next-step h complete
    }

    // ---- epilogue: y for final step ----
    if (tid >= 320 && tid < 332 && j < BPG) {
        const int f = (tid - 320) >> 2, ch = (tid - 320) & 3;
        float s = 0.f;
        const int u0 = ch * 100;
        #pragma unroll 4
        for (int u = u0; u < u0 + 100; ++u)
            s += hsh[j][u] * W_out[u * 3 + f];
        yred[f][ch] = s;
    }
    __syncthreads();
    if (tid < 3 && j < BPG)
        out[((size_t)(gr * BPG + j) * TLEN + (TLEN - 1)) * 3 + tid] =
            b_out[tid] + yred[tid][0] + yred[tid][1] + yred[tid][2] + yred[tid][3];
#undef FMA4
}

// ---- fallback: proven round-1 single-block-per-batch kernel ----
__global__ __launch_bounds__(512) void lstm_fused_fb(
    const float* __restrict__ x, const float* __restrict__ W_x,
    const float* __restrict__ W_h, const float* __restrict__ bvec,
    const float* __restrict__ p_i, const float* __restrict__ p_f,
    const float* __restrict__ p_o, const float* __restrict__ W_out,
    const float* __restrict__ b_out, float* __restrict__ out)
{
    const int b = blockIdx.x, tid = threadIdx.x;
    const int lane = tid & 63, wv = tid >> 6;
    __shared__ float hsh[UNITS], csh[UNITS], zsh[GATES], xb[3], red[8][3];
    const float4* Wh4 = (const float4*)W_h;
    const int g = tid;
    float4 wx0, wx1, wx2, bb;
    if (g < GATES/4) {
        const float4* Wx4 = (const float4*)W_x;
        wx0 = Wx4[0*400 + g]; wx1 = Wx4[1*400 + g]; wx2 = Wx4[2*400 + g];
        bb  = ((const float4*)bvec)[g];
    }
    float piu=0.f,pfu=0.f,pou=0.f,wo0=0.f,wo1=0.f,wo2=0.f;
    if (tid < UNITS) {
        piu=p_i[tid]; pfu=p_f[tid]; pou=p_o[tid];
        wo0=W_out[tid*3]; wo1=W_out[tid*3+1]; wo2=W_out[tid*3+2];
        hsh[tid]=0.f; csh[tid]=0.f;
    }
    const float bo = (tid<3)?b_out[tid]:0.f;
    const float* xrow = x + (size_t)b*TLEN*3;
    float* orow = out + (size_t)b*TLEN*3;
    for (int t=0;t<TLEN;++t){
        if (tid<3) xb[tid]=xrow[t*3+tid];
        __syncthreads();
        const float x0=xb[0],x1=xb[1],x2=xb[2];
        if (g < GATES/4){
            float4 acc;
            acc.x=fmaf(x0,wx0.x,fmaf(x1,wx1.x,fmaf(x2,wx2.x,bb.x)));
            acc.y=fmaf(x0,wx0.y,fmaf(x1,wx1.y,fmaf(x2,wx2.y,bb.y)));
            acc.z=fmaf(x0,wx0.z,fmaf(x1,wx1.z,fmaf(x2,wx2.z,bb.z)));
            acc.w=fmaf(x0,wx0.w,fmaf(x1,wx1.w,fmaf(x2,wx2.w,bb.w)));
            const float4* wp=Wh4+g;
            #pragma unroll 8
            for(int k=0;k<UNITS;++k){
                const float hk=hsh[k]; const float4 w=wp[(size_t)k*400];
                acc.x=fmaf(hk,w.x,acc.x); acc.y=fmaf(hk,w.y,acc.y);
                acc.z=fmaf(hk,w.z,acc.z); acc.w=fmaf(hk,w.w,acc.w);
            }
            ((float4*)zsh)[g]=acc;
        }
        __syncthreads();
        float s0=0.f,s1=0.f,s2=0.f;
        if (tid<UNITS){
            const float cc=csh[tid];
            const float zi=zsh[tid],zf=zsh[tid+UNITS],zg=zsh[tid+2*UNITS],zo=zsh[tid+3*UNITS];
            const float ig=sigmoid_(fmaf(piu,cc,zi));
            const float fg=sigmoid_(fmaf(pfu,cc,zf));
            const float gg=tanh_(zg);
            const float cn=fmaf(fg,cc,ig*gg);
            const float og=sigmoid_(fmaf(pou,cn,zo));
            const float hn=og*tanh_(cn);
            csh[tid]=cn; hsh[tid]=hn;
            s0=hn*wo0; s1=hn*wo1; s2=hn*wo2;
        }
        #pragma unroll
        for(int off=32;off;off>>=1){
            s0+=__shfl_down(s0,off); s1+=__shfl_down(s1,off); s2+=__shfl_down(s2,off);
        }
        if(lane==0){red[wv][0]=s0;red[wv][1]=s1;red[wv][2]=s2;}
        __syncthreads();
        if(tid<3){
            float r=bo;
            #pragma unroll
            for(int w2=0;w2<8;++w2) r+=red[w2][tid];
            orow[t*3+tid]=r;
        }
    }
}

extern "C" void kernel_launch(void* const* d_in, const int* in_sizes, int n_in,
                              void* d_out, int out_size, void* d_ws, size_t ws_size,
                              hipStream_t stream) {
    const float* x     = (const float*)d_in[0];
    const float* W_x   = (const float*)d_in[1];
    const float* W_h   = (const float*)d_in[2];
    const float* b     = (const float*)d_in[3];
    const float* p_i   = (const float*)d_in[4];
    const float* p_f   = (const float*)d_in[5];
    const float* p_o   = (const float*)d_in[6];
    const float* W_out = (const float*)d_in[7];
    const float* b_out = (const float*)d_in[8];
    float* out = (float*)d_out;

    if (ws_size < WS_FULL) {
        lstm_fused_fb<<<BATCH, 512, 0, stream>>>(x, W_x, W_h, b, p_i, p_f, p_o,
                                                 W_out, b_out, out);
        return;
    }

    uint8_t* ws = (uint8_t*)d_ws;
    float* wbuf = (float*)(ws + WBUF_OFF);
    unsigned long long* hbuf = (unsigned long long*)(ws + HBUF_OFF);

    hipMemsetAsync(hbuf, 0, HBUF_SZ, stream);    // kill stale tags (graph replay)
    reorder_w<<<(NBLK * UNITS * CPB + 255) / 256, 256, 0, stream>>>(W_h, wbuf);
    lstm_mb<<<NGRP * NBLK, 512, 0, stream>>>(x, W_x, b, p_i, p_f, p_o,
                                             W_out, b_out, wbuf, hbuf, out);
}

// Round 12
// 4785.057 us; speedup vs baseline: 3.3799x; 3.3799x over previous
//
#include <hip/hip_runtime.h>
#include <hip/hip_bf16.h>
#include <stdint.h>

#define UNITS 400
#define GATES 1600
#define TLEN  1000
#define BATCH 64

#define NBLK 16        // blocks per group
#define NGRP 16        // groups (group XCD-local: blockIdx%8 == gr%8)
#define BPG  4         // batches per group
#define UPB  25        // units per block
#define CPB  100       // cols per block
#define KK   20        // k-split (z-threads = 500)
#define KCH  20        // k rows per z-thread

// d_ws layout
#define WBUF_OFF 0
#define WBUF_SZ  (NBLK*UNITS*CPB*4)      // 2,560,000
#define HBUF_OFF (WBUF_OFF + WBUF_SZ)
#define HBUF_SZ  (2*BATCH*UNITS*8)       //   409,600 (u64 {tag,val}, [p][b][u])
#define WS_FULL  ((size_t)(HBUF_OFF + HBUF_SZ))

#define SPIN_CAP (1 << 20)   // watchdog: convert a protocol stall into absmax fail

__device__ __forceinline__ float sigmoid_(float x) {
    return 1.0f / (1.0f + __expf(-x));
}
__device__ __forceinline__ float tanh_(float x) {
    return 1.0f - 2.0f / (__expf(2.0f * x) + 1.0f);
}

// ---- one-time reorder: wbuf[j][k][c] = W_h[k][(c/25)*400 + j*25 + c%25] ----
__global__ void reorder_w(const float* __restrict__ W_h, float* __restrict__ wbuf) {
    int i = blockIdx.x * 256 + threadIdx.x;
    if (i >= NBLK * UNITS * CPB) return;
    int c = i % CPB;
    int k = (i / CPB) % UNITS;
    int j = i / (CPB * UNITS);
    int col = (c / UPB) * UNITS + j * UPB + (c % UPB);
    wbuf[i] = W_h[k * GATES + col];
}

__global__ __launch_bounds__(512, 1) void lstm_mb(
    const float* __restrict__ x,      // [B,T,3]
    const float* __restrict__ W_x,    // [3,1600]
    const float* __restrict__ bvec,   // [1600]
    const float* __restrict__ p_i,
    const float* __restrict__ p_f,
    const float* __restrict__ p_o,
    const float* __restrict__ W_out,  // [400,3]
    const float* __restrict__ b_out,  // [3]
    const float* __restrict__ wbuf,
    unsigned long long* __restrict__ hbuf,   // [2][B][U] {tag,val}
    float* __restrict__ out)                 // [B,T,3]
{
    const int gr  = blockIdx.x % NGRP;   // XCD-local grouping (perf only)
    const int j   = blockIdx.x / NGRP;
    const int tid = threadIdx.x;

    __shared__ float hsh[BPG][UNITS];        //  6.4 KB
    __shared__ float zpart[KK][BPG][CPB];    // 32.0 KB
    __shared__ float wosh[UNITS][3];         //  4.8 KB
    __shared__ float xsh[BPG][4];
    __shared__ float yred[3][4];

    const float* wslice = wbuf + (size_t)j * UNITS * CPB;

    // ---- roles ----
    const int  kk = tid / UPB, cq = tid % UPB;   // z-role: tid < 500
    const bool zrole = (tid < KK * UPB);
    const int  k0 = kk * KCH;

    const int  gb = tid / UPB, gu = tid % UPB;   // gate-role: tid < 100
    const bool grole = (tid < BPG * UPB);

    const bool prole = (tid >= 100) && (tid < 100 + UNITS);  // 400 poll threads
    const int  pu = tid - 100;

    // ---- gate-thread hoists ----
    int unit = 0, batch = 0;
    float wxr[3][4], bbv[4];
    float piu = 0.f, pfu = 0.f, pou = 0.f, cc = 0.f;
    if (grole) {
        unit  = j * UPB + gu;
        batch = gr * BPG + gb;
        #pragma unroll
        for (int g = 0; g < 4; ++g) {
            const int gcol = g * UNITS + unit;
            wxr[0][g] = W_x[gcol];
            wxr[1][g] = W_x[GATES + gcol];
            wxr[2][g] = W_x[2 * GATES + gcol];
            bbv[g]    = bvec[gcol];
        }
        piu = p_i[unit]; pfu = p_f[unit]; pou = p_o[unit];
    }
    if (tid < UNITS) {
        wosh[tid][0] = W_out[tid * 3 + 0];
        wosh[tid][1] = W_out[tid * 3 + 1];
        wosh[tid][2] = W_out[tid * 3 + 2];
        #pragma unroll
        for (int b = 0; b < BPG; ++b) hsh[b][tid] = 0.f;
    }
    __syncthreads();

#define FMA4(A, s, W) \
    A.x = fmaf(s, W.x, A.x); A.y = fmaf(s, W.y, A.y); \
    A.z = fmaf(s, W.z, A.z); A.w = fmaf(s, W.w, A.w);

    for (int t = 0; t < TLEN; ++t) {
        const int p = t & 1;

        // ========== A: z-partials (L2-streamed weights) / x stage / y(t-1) =====
        if (zrole) {
            float4 A0 = {0,0,0,0}, A1 = A0, A2 = A0, A3 = A0;
            #pragma unroll
            for (int ro = 0; ro < KCH; ro += 4) {
                const float* wp = wslice + (size_t)(k0 + ro) * CPB + (cq << 2);
                const float4 w0 = *(const float4*)(wp);
                const float4 w1 = *(const float4*)(wp + CPB);
                const float4 w2 = *(const float4*)(wp + 2 * CPB);
                const float4 w3 = *(const float4*)(wp + 3 * CPB);
                const float4 h0 = *(const float4*)&hsh[0][k0 + ro];
                const float4 h1 = *(const float4*)&hsh[1][k0 + ro];
                const float4 h2 = *(const float4*)&hsh[2][k0 + ro];
                const float4 h3 = *(const float4*)&hsh[3][k0 + ro];
                FMA4(A0, h0.x, w0) FMA4(A0, h0.y, w1) FMA4(A0, h0.z, w2) FMA4(A0, h0.w, w3)
                FMA4(A1, h1.x, w0) FMA4(A1, h1.y, w1) FMA4(A1, h1.z, w2) FMA4(A1, h1.w, w3)
                FMA4(A2, h2.x, w0) FMA4(A2, h2.y, w1) FMA4(A2, h2.z, w2) FMA4(A2, h2.w, w3)
                FMA4(A3, h3.x, w0) FMA4(A3, h3.y, w1) FMA4(A3, h3.z, w2) FMA4(A3, h3.w, w3)
            }
            *(float4*)&zpart[kk][0][cq << 2] = A0;
            *(float4*)&zpart[kk][1][cq << 2] = A1;
            *(float4*)&zpart[kk][2][cq << 2] = A2;
            *(float4*)&zpart[kk][3][cq << 2] = A3;
        } else {
            const int i = tid - 500;                    // 0..11
            const int ib = i / 3, iff = i % 3;
            xsh[ib][iff] = x[((size_t)(gr * BPG + ib) * TLEN + t) * 3 + iff];
            if (j < BPG && t > 0) {
                // y partial for step t-1 (hsh = h_{t-1}); block j owns batch gr*4+j
                const int f = i % 3, ch = i / 3;        // 4 chunks x 3 feats
                float s = 0.f;
                const int u0 = ch * 100;
                #pragma unroll 4
                for (int u = u0; u < u0 + 100; ++u)
                    s += hsh[j][u] * wosh[u][f];
                yred[f][ch] = s;
            }
        }
        __syncthreads();   // zpart/xsh/yred ready; hsh reads done

        // ========== B: fused reduce + gates + publish (coalesced [p][b][u]) ====
        if (grole) {
            const float x0 = xsh[gb][0], x1 = xsh[gb][1], x2 = xsh[gb][2];
            float s[4];
            #pragma unroll
            for (int g = 0; g < 4; ++g) {
                float acc = fmaf(x0, wxr[0][g],
                            fmaf(x1, wxr[1][g],
                            fmaf(x2, wxr[2][g], bbv[g])));
                #pragma unroll
                for (int q = 0; q < KK; ++q) acc += zpart[q][gb][g * UPB + gu];
                s[g] = acc;
            }
            const float ig = sigmoid_(fmaf(piu, cc, s[0]));
            const float fg = sigmoid_(fmaf(pfu, cc, s[1]));
            const float gg = tanh_(s[2]);
            const float cn = fmaf(fg, cc, ig * gg);
            const float og = sigmoid_(fmaf(pou, cn, s[3]));
            const float hn = og * tanh_(cn);
            cc = cn;
            hsh[gb][unit] = hn;
            const unsigned long long pkt =
                ((unsigned long long)(unsigned)(t + 1) << 32) |
                (unsigned long long)__float_as_uint(hn);
            __hip_atomic_store(&hbuf[(size_t)p * BATCH * UNITS + (size_t)batch * UNITS + unit],
                               pkt, __ATOMIC_RELAXED, __HIP_MEMORY_SCOPE_AGENT);
        } else if (t > 0 && j < BPG && tid >= 500 && tid < 503) {
            // y final write for t-1 (off critical path)
            const int f = tid - 500;
            out[((size_t)(gr * BPG + j) * TLEN + (t - 1)) * 3 + f] =
                b_out[f] + yred[f][0] + yred[f][1] + yred[f][2] + yred[f][3];
        }
        __syncthreads();   // publishes drained (vmcnt) before any poll begins

        // ========== C: poll (r6-proven shape: one unit, 4 strided loads) =======
        if (prole) {
            const unsigned want = (unsigned)(t + 1);
            const size_t base = (size_t)p * BATCH * UNITS
                              + (size_t)(gr * BPG) * UNITS + pu;
            unsigned long long v0, v1, v2, v3;
            int guard = 0;
            for (;;) {
                v0 = __hip_atomic_load(&hbuf[base + 0 * UNITS], __ATOMIC_RELAXED, __HIP_MEMORY_SCOPE_AGENT);
                v1 = __hip_atomic_load(&hbuf[base + 1 * UNITS], __ATOMIC_RELAXED, __HIP_MEMORY_SCOPE_AGENT);
                v2 = __hip_atomic_load(&hbuf[base + 2 * UNITS], __ATOMIC_RELAXED, __HIP_MEMORY_SCOPE_AGENT);
                v3 = __hip_atomic_load(&hbuf[base + 3 * UNITS], __ATOMIC_RELAXED, __HIP_MEMORY_SCOPE_AGENT);
                const unsigned ok =
                    ((unsigned)(v0 >> 32) == want) & ((unsigned)(v1 >> 32) == want) &
                    ((unsigned)(v2 >> 32) == want) & ((unsigned)(v3 >> 32) == want);
                if (ok) break;
                if (++guard > SPIN_CAP) break;   // watchdog: fail loud, not hang
                __builtin_amdgcn_s_sleep(2);
            }
            hsh[0][pu] = __uint_as_float((unsigned)v0);
            hsh[1][pu] = __uint_as_float((unsigned)v1);
            hsh[2][pu] = __uint_as_float((unsigned)v2);
            hsh[3][pu] = __uint_as_float((unsigned)v3);
        }
        __syncthreads();   // hsh = h_t complete
    }

    // ---- epilogue: y for the final step ----
    if (tid >= 500 && j < BPG) {
        const int i = tid - 500;
        const int f = i % 3, ch = i / 3;
        float s = 0.f;
        const int u0 = ch * 100;
        #pragma unroll 4
        for (int u = u0; u < u0 + 100; ++u)
            s += hsh[j][u] * wosh[u][f];
        yred[f][ch] = s;
    }
    __syncthreads();
    if (tid < 3 && j < BPG)
        out[((size_t)(gr * BPG + j) * TLEN + (TLEN - 1)) * 3 + tid] =
            b_out[tid] + yred[tid][0] + yred[tid][1] + yred[tid][2] + yred[tid][3];
#undef FMA4
}

// ---- fallback: proven round-1 single-block-per-batch kernel ----
__global__ __launch_bounds__(512) void lstm_fused_fb(
    const float* __restrict__ x, const float* __restrict__ W_x,
    const float* __restrict__ W_h, const float* __restrict__ bvec,
    const float* __restrict__ p_i, const float* __restrict__ p_f,
    const float* __restrict__ p_o, const float* __restrict__ W_out,
    const float* __restrict__ b_out, float* __restrict__ out)
{
    const int b = blockIdx.x, tid = threadIdx.x;
    const int lane = tid & 63, wv = tid >> 6;
    __shared__ float hsh[UNITS], csh[UNITS], zsh[GATES], xb[3], red[8][3];
    const float4* Wh4 = (const float4*)W_h;
    const int g = tid;
    float4 wx0, wx1, wx2, bb;
    if (g < GATES/4) {
        const float4* Wx4 = (const float4*)W_x;
        wx0 = Wx4[0*400 + g]; wx1 = Wx4[1*400 + g]; wx2 = Wx4[2*400 + g];
        bb  = ((const float4*)bvec)[g];
    }
    float piu=0.f,pfu=0.f,pou=0.f,wo0=0.f,wo1=0.f,wo2=0.f;
    if (tid < UNITS) {
        piu=p_i[tid]; pfu=p_f[tid]; pou=p_o[tid];
        wo0=W_out[tid*3]; wo1=W_out[tid*3+1]; wo2=W_out[tid*3+2];
        hsh[tid]=0.f; csh[tid]=0.f;
    }
    const float bo = (tid<3)?b_out[tid]:0.f;
    const float* xrow = x + (size_t)b*TLEN*3;
    float* orow = out + (size_t)b*TLEN*3;
    for (int t=0;t<TLEN;++t){
        if (tid<3) xb[tid]=xrow[t*3+tid];
        __syncthreads();
        const float x0=xb[0],x1=xb[1],x2=xb[2];
        if (g < GATES/4){
            float4 acc;
            acc.x=fmaf(x0,wx0.x,fmaf(x1,wx1.x,fmaf(x2,wx2.x,bb.x)));
            acc.y=fmaf(x0,wx0.y,fmaf(x1,wx1.y,fmaf(x2,wx2.y,bb.y)));
            acc.z=fmaf(x0,wx0.z,fmaf(x1,wx1.z,fmaf(x2,wx2.z,bb.z)));
            acc.w=fmaf(x0,wx0.w,fmaf(x1,wx1.w,fmaf(x2,wx2.w,bb.w)));
            const float4* wp=Wh4+g;
            #pragma unroll 8
            for(int k=0;k<UNITS;++k){
                const float hk=hsh[k]; const float4 w=wp[(size_t)k*400];
                acc.x=fmaf(hk,w.x,acc.x); acc.y=fmaf(hk,w.y,acc.y);
                acc.z=fmaf(hk,w.z,acc.z); acc.w=fmaf(hk,w.w,acc.w);
            }
            ((float4*)zsh)[g]=acc;
        }
        __syncthreads();
        float s0=0.f,s1=0.f,s2=0.f;
        if (tid<UNITS){
            const float cc=csh[tid];
            const float zi=zsh[tid],zf=zsh[tid+UNITS],zg=zsh[tid+2*UNITS],zo=zsh[tid+3*UNITS];
            const float ig=sigmoid_(fmaf(piu,cc,zi));
            const float fg=sigmoid_(fmaf(pfu,cc,zf));
            const float gg=tanh_(zg);
            const float cn=fmaf(fg,cc,ig*gg);
            const float og=sigmoid_(fmaf(pou,cn,zo));
            const float hn=og*tanh_(cn);
            csh[tid]=cn; hsh[tid]=hn;
            s0=hn*wo0; s1=hn*wo1; s2=hn*wo2;
        }
        #pragma unroll
        for(int off=32;off;off>>=1){
            s0+=__shfl_down(s0,off); s1+=__shfl_down(s1,off); s2+=__shfl_down(s2,off);
        }
        if(lane==0){red[wv][0]=s0;red[wv][1]=s1;red[wv][2]=s2;}
        __syncthreads();
        if(tid<3){
            float r=bo;
            #pragma unroll
            for(int w2=0;w2<8;++w2) r+=red[w2][tid];
            orow[t*3+tid]=r;
        }
    }
}

extern "C" void kernel_launch(void* const* d_in, const int* in_sizes, int n_in,
                              void* d_out, int out_size, void* d_ws, size_t ws_size,
                              hipStream_t stream) {
    const float* x     = (const float*)d_in[0];
    const float* W_x   = (const float*)d_in[1];
    const float* W_h   = (const float*)d_in[2];
    const float* b     = (const float*)d_in[3];
    const float* p_i   = (const float*)d_in[4];
    const float* p_f   = (const float*)d_in[5];
    const float* p_o   = (const float*)d_in[6];
    const float* W_out = (const float*)d_in[7];
    const float* b_out = (const float*)d_in[8];
    float* out = (float*)d_out;

    if (ws_size < WS_FULL) {
        lstm_fused_fb<<<BATCH, 512, 0, stream>>>(x, W_x, W_h, b, p_i, p_f, p_o,
                                                 W_out, b_out, out);
        return;
    }

    uint8_t* ws = (uint8_t*)d_ws;
    float* wbuf = (float*)(ws + WBUF_OFF);
    unsigned long long* hbuf = (unsigned long long*)(ws + HBUF_OFF);

    hipMemsetAsync(hbuf, 0, HBUF_SZ, stream);    // kill stale tags (graph replay)
    reorder_w<<<(NBLK * UNITS * CPB + 255) / 256, 256, 0, stream>>>(W_h, wbuf);
    lstm_mb<<<NGRP * NBLK, 512, 0, stream>>>(x, W_x, b, p_i, p_f, p_o,
                                             W_out, b_out, wbuf, hbuf, out);
}

// Round 13
// 4522.539 us; speedup vs baseline: 3.5761x; 1.0580x over previous
//
#include <hip/hip_runtime.h>
#include <hip/hip_bf16.h>
#include <stdint.h>

#define UNITS 400
#define GATES 1600
#define TLEN  1000
#define BATCH 64

#define NBLK 8         // blocks per group (weight slices)
#define NGRP 32        // groups
#define BPG  2         // batches per group
#define UPB  50        // units per block
#define CPB  200       // cols per block
#define KK   10        // k-split
#define KCH  40        // k rows per z-thread

// d_ws layout
#define WBUF_OFF  0
#define WBUF_SZ   (NBLK*UNITS*CPB*2)                 // 1,280,000 (bf16)
#define HBUF_OFF  (WBUF_OFF + WBUF_SZ)
#define HBUF_SZ   (2*BATCH*UNITS*8)                  //   409,600 (u64 {tag,val})
#define PART_OFF  (HBUF_OFF + HBUF_SZ)
#define PART_SZ   (NGRP*NBLK*BPG*3*TLEN*4)           // 6,144,000
#define WS_FULL   ((size_t)PART_OFF + PART_SZ)

#define SPIN_CAP (1 << 20)   // watchdog: stall -> loud absmax fail, not a hang

__device__ __forceinline__ float sigmoid_(float x) {
    return 1.0f / (1.0f + __expf(-x));
}
__device__ __forceinline__ float tanh_(float x) {
    return 1.0f - 2.0f / (__expf(2.0f * x) + 1.0f);
}

// ---- one-time reorder + bf16 cast: wbuf[j][k][c] = bf16(W_h[k][(c/50)*400 + j*50 + c%50]) ----
__global__ void reorder_w(const float* __restrict__ W_h, __hip_bfloat16* __restrict__ wbuf) {
    int i = blockIdx.x * 256 + threadIdx.x;
    if (i >= NBLK * UNITS * CPB) return;
    int c = i % CPB;
    int k = (i / CPB) % UNITS;
    int j = i / (CPB * UNITS);
    int col = (c / UPB) * UNITS + j * UPB + (c % UPB);
    wbuf[i] = __float2bfloat16(W_h[k * GATES + col]);
}

// ---- main: r8 structure, bf16 weight stream, tag-in-data exchange, 2 syncs/step ----
__global__ __launch_bounds__(512, 1) void lstm_mb(
    const float* __restrict__ x,      // [B,T,3]
    const float* __restrict__ W_x,    // [3,1600]
    const float* __restrict__ bvec,   // [1600]
    const float* __restrict__ p_i,
    const float* __restrict__ p_f,
    const float* __restrict__ p_o,
    const float* __restrict__ W_out,  // [400,3]
    const __hip_bfloat16* __restrict__ wbuf,
    unsigned long long* __restrict__ hbuf,   // [2][B][U] {tag,val}
    float*       __restrict__ part,          // [NGRP*NBLK][BPG][3][TLEN]
    float*       __restrict__ out)           // (finish_y writes out)
{
    const int gr  = blockIdx.x % NGRP;   // XCD-local heuristic (perf only)
    const int j   = blockIdx.x / NGRP;
    const int tid = threadIdx.x;

    __shared__ float hsh[BPG][UNITS];          // 3.2 KB
    __shared__ float zpart[KK][BPG][CPB];      // 16 KB
    __shared__ float wosh[UPB][3];
    __shared__ float xsh[BPG][4];

    const __hip_bfloat16* wsl = wbuf + (size_t)j * UNITS * CPB;

    // ---- roles (exactly r8) ----
    const int kk = tid / 50, cq = tid % 50;       // z-role: tid < 500
    const bool zrole = (tid < KK * 50);
    const int k0 = kk * KCH;

    const int gb = tid / UPB, gu = tid % UPB;     // gate-role: tid < 100
    const bool grole = (tid < BPG * UPB);

    const bool prole = (tid < UNITS) && (tid / UPB != j);  // poll-role: skip own slice
    const bool yrole = (tid >= 500) && (tid < 500 + BPG * 3);
    const int yb = (tid - 500) / 3, yf = (tid - 500) % 3;
    const bool xrole = (tid >= 500 + BPG * 3) && (tid < 500 + 2 * BPG * 3);
    const int xb2 = (tid - 500 - BPG * 3) / 3, xf = (tid - 500 - BPG * 3) % 3;

    // ---- gate-thread hoists ----
    int unit = 0, batch = 0;
    float wxr[3][4], bb[4];
    float piu = 0.f, pfu = 0.f, pou = 0.f, cc = 0.f;
    if (grole) {
        unit  = j * UPB + gu;
        batch = gr * BPG + gb;
        #pragma unroll
        for (int g = 0; g < 4; ++g) {
            const int gcol = g * UNITS + unit;
            wxr[0][g] = W_x[0 * GATES + gcol];
            wxr[1][g] = W_x[1 * GATES + gcol];
            wxr[2][g] = W_x[2 * GATES + gcol];
            bb[g]     = bvec[gcol];
        }
        piu = p_i[unit]; pfu = p_f[unit]; pou = p_o[unit];
    }
    if (tid < UPB * 3) wosh[tid / 3][tid % 3] = W_out[(j * UPB + tid / 3) * 3 + (tid % 3)];

    // ---- state init ----
    if (tid < UNITS) { hsh[0][tid] = 0.f; hsh[1][tid] = 0.f; }
    __syncthreads();

// one weight row (4 bf16 cols in uint2 U) applied to 2 batches' h elements
#define WROW(U, HE0, HE1) {                                                        \
    const float w0 = __uint_as_float((U).x << 16);                                 \
    const float w1 = __uint_as_float((U).x & 0xffff0000u);                         \
    const float w2 = __uint_as_float((U).y << 16);                                 \
    const float w3 = __uint_as_float((U).y & 0xffff0000u);                         \
    a0.x = fmaf(HE0, w0, a0.x); a0.y = fmaf(HE0, w1, a0.y);                        \
    a0.z = fmaf(HE0, w2, a0.z); a0.w = fmaf(HE0, w3, a0.w);                        \
    a1.x = fmaf(HE1, w0, a1.x); a1.y = fmaf(HE1, w1, a1.y);                        \
    a1.z = fmaf(HE1, w2, a1.z); a1.w = fmaf(HE1, w3, a1.w); }

    for (int t = 0; t < TLEN; ++t) {
        const int p = t & 1;

        // ================= A: z-partials (bf16 stream) / y(t-1) / x stage =======
        if (zrole) {
            float4 a0 = {0,0,0,0}, a1 = a0;
            #pragma unroll
            for (int ro = 0; ro < KCH; ro += 4) {
                const int kr = k0 + ro;
                const uint2 u0 = *(const uint2*)(wsl + (size_t)(kr + 0) * CPB + (cq << 2));
                const uint2 u1 = *(const uint2*)(wsl + (size_t)(kr + 1) * CPB + (cq << 2));
                const uint2 u2 = *(const uint2*)(wsl + (size_t)(kr + 2) * CPB + (cq << 2));
                const uint2 u3 = *(const uint2*)(wsl + (size_t)(kr + 3) * CPB + (cq << 2));
                const float4 h0 = *(const float4*)&hsh[0][kr];
                const float4 h1 = *(const float4*)&hsh[1][kr];
                WROW(u0, h0.x, h1.x)
                WROW(u1, h0.y, h1.y)
                WROW(u2, h0.z, h1.z)
                WROW(u3, h0.w, h1.w)
            }
            *(float4*)&zpart[kk][0][cq * 4] = a0;
            *(float4*)&zpart[kk][1][cq * 4] = a1;
        } else if (yrole && t > 0) {
            // y partial for step t-1 (hsh holds that step's output h) — ALL blocks
            float s = 0.f;
            #pragma unroll
            for (int u = 0; u < UPB; ++u)
                s += hsh[yb][j * UPB + u] * wosh[u][yf];
            part[(((size_t)(gr * NBLK + j) * BPG + yb) * 3 + yf) * TLEN + (t - 1)] = s;
        } else if (xrole) {
            xsh[xb2][xf] = x[((size_t)(gr * BPG + xb2) * TLEN + t) * 3 + xf];
        }
        __syncthreads();   // zpart + xsh ready; hsh reads done

        // ================= B: fused reduce + gates + publish (tid<100) ==========
        if (grole) {
            const float x0 = xsh[gb][0], x1 = xsh[gb][1], x2 = xsh[gb][2];
            float s[4];
            #pragma unroll
            for (int g = 0; g < 4; ++g) {
                float acc = fmaf(x0, wxr[0][g],
                            fmaf(x1, wxr[1][g],
                            fmaf(x2, wxr[2][g], bb[g])));
                #pragma unroll
                for (int q = 0; q < KK; ++q) acc += zpart[q][gb][g * UPB + gu];
                s[g] = acc;
            }
            const float ig = sigmoid_(fmaf(piu, cc, s[0]));
            const float fg = sigmoid_(fmaf(pfu, cc, s[1]));
            const float gg = tanh_(s[2]);
            const float cn = fmaf(fg, cc, ig * gg);
            const float og = sigmoid_(fmaf(pou, cn, s[3]));
            const float hn = og * tanh_(cn);
            cc = cn;
            hsh[gb][unit] = hn;    // own slice locally
            const unsigned long long pkt =
                ((unsigned long long)(unsigned)(t + 1) << 32) |
                (unsigned long long)__float_as_uint(hn);
            __hip_atomic_store(&hbuf[(size_t)p * BATCH * UNITS + (size_t)batch * UNITS + unit],
                               pkt, __ATOMIC_RELAXED, __HIP_MEMORY_SCOPE_AGENT);
        }

        // ================= C: poll remote slices (overlaps B) ===================
        if (prole) {
            const unsigned want = (unsigned)(t + 1);
            const size_t base = (size_t)p * BATCH * UNITS
                              + (size_t)(gr * BPG) * UNITS + tid;
            unsigned long long v0, v1;
            int guard = 0;
            for (;;) {
                v0 = __hip_atomic_load(&hbuf[base],
                                       __ATOMIC_RELAXED, __HIP_MEMORY_SCOPE_AGENT);
                v1 = __hip_atomic_load(&hbuf[base + UNITS],
                                       __ATOMIC_RELAXED, __HIP_MEMORY_SCOPE_AGENT);
                if ((unsigned)(v0 >> 32) == want && (unsigned)(v1 >> 32) == want) break;
                if (++guard > SPIN_CAP) break;   // watchdog
                __builtin_amdgcn_s_sleep(2);
            }
            hsh[0][tid] = __uint_as_float((unsigned)v0);
            hsh[1][tid] = __uint_as_float((unsigned)v1);
        }
        __syncthreads();   // hsh = h_{t+1} complete
    }

    // ---- epilogue: y partial for final step ----
    if (yrole) {
        float s = 0.f;
        #pragma unroll
        for (int u = 0; u < UPB; ++u)
            s += hsh[yb][j * UPB + u] * wosh[u][yf];
        part[(((size_t)(gr * NBLK + j) * BPG + yb) * 3 + yf) * TLEN + (TLEN - 1)] = s;
    }
#undef WROW
}

// ---- post-kernel: out[b][t][f] = b_out[f] + sum_j part[gr][j][gb][f][t] ----
__global__ void finish_y(const float* __restrict__ part,
                         const float* __restrict__ b_out,
                         float* __restrict__ out) {
    int i = blockIdx.x * 256 + threadIdx.x;
    if (i >= BATCH * TLEN * 3) return;
    const int f = i % 3;
    const int bt = i / 3;
    const int t = bt % TLEN;
    const int b = bt / TLEN;
    const int gr = b / BPG, gb = b % BPG;
    float s = b_out[f];
    #pragma unroll
    for (int j = 0; j < NBLK; ++j)
        s += part[(((size_t)(gr * NBLK + j) * BPG + gb) * 3 + f) * TLEN + t];
    out[i] = s;
}

// ---- fallback: proven round-1 single-block-per-batch kernel ----
__global__ __launch_bounds__(512) void lstm_fused_fb(
    const float* __restrict__ x, const float* __restrict__ W_x,
    const float* __restrict__ W_h, const float* __restrict__ bvec,
    const float* __restrict__ p_i, const float* __restrict__ p_f,
    const float* __restrict__ p_o, const float* __restrict__ W_out,
    const float* __restrict__ b_out, float* __restrict__ out)
{
    const int b = blockIdx.x, tid = threadIdx.x;
    const int lane = tid & 63, wv = tid >> 6;
    __shared__ float hsh[UNITS], csh[UNITS], zsh[GATES], xb[3], red[8][3];
    const float4* Wh4 = (const float4*)W_h;
    const int g = tid;
    float4 wx0, wx1, wx2, bb;
    if (g < GATES/4) {
        const float4* Wx4 = (const float4*)W_x;
        wx0 = Wx4[0*400 + g]; wx1 = Wx4[1*400 + g]; wx2 = Wx4[2*400 + g];
        bb  = ((const float4*)bvec)[g];
    }
    float piu=0.f,pfu=0.f,pou=0.f,wo0=0.f,wo1=0.f,wo2=0.f;
    if (tid < UNITS) {
        piu=p_i[tid]; pfu=p_f[tid]; pou=p_o[tid];
        wo0=W_out[tid*3]; wo1=W_out[tid*3+1]; wo2=W_out[tid*3+2];
        hsh[tid]=0.f; csh[tid]=0.f;
    }
    const float bo = (tid<3)?b_out[tid]:0.f;
    const float* xrow = x + (size_t)b*TLEN*3;
    float* orow = out + (size_t)b*TLEN*3;
    for (int t=0;t<TLEN;++t){
        if (tid<3) xb[tid]=xrow[t*3+tid];
        __syncthreads();
        const float x0=xb[0],x1=xb[1],x2=xb[2];
        if (g < GATES/4){
            float4 acc;
            acc.x=fmaf(x0,wx0.x,fmaf(x1,wx1.x,fmaf(x2,wx2.x,bb.x)));
            acc.y=fmaf(x0,wx0.y,fmaf(x1,wx1.y,fmaf(x2,wx2.y,bb.y)));
            acc.z=fmaf(x0,wx0.z,fmaf(x1,wx1.z,fmaf(x2,wx2.z,bb.z)));
            acc.w=fmaf(x0,wx0.w,fmaf(x1,wx1.w,fmaf(x2,wx2.w,bb.w)));
            const float4* wp=Wh4+g;
            #pragma unroll 8
            for(int k=0;k<UNITS;++k){
                const float hk=hsh[k]; const float4 w=wp[(size_t)k*400];
                acc.x=fmaf(hk,w.x,acc.x); acc.y=fmaf(hk,w.y,acc.y);
                acc.z=fmaf(hk,w.z,acc.z); acc.w=fmaf(hk,w.w,acc.w);
            }
            ((float4*)zsh)[g]=acc;
        }
        __syncthreads();
        float s0=0.f,s1=0.f,s2=0.f;
        if (tid<UNITS){
            const float cc=csh[tid];
            const float zi=zsh[tid],zf=zsh[tid+UNITS],zg=zsh[tid+2*UNITS],zo=zsh[tid+3*UNITS];
            const float ig=sigmoid_(fmaf(piu,cc,zi));
            const float fg=sigmoid_(fmaf(pfu,cc,zf));
            const float gg=tanh_(zg);
            const float cn=fmaf(fg,cc,ig*gg);
            const float og=sigmoid_(fmaf(pou,cn,zo));
            const float hn=og*tanh_(cn);
            csh[tid]=cn; hsh[tid]=hn;
            s0=hn*wo0; s1=hn*wo1; s2=hn*wo2;
        }
        #pragma unroll
        for(int off=32;off;off>>=1){
            s0+=__shfl_down(s0,off); s1+=__shfl_down(s1,off); s2+=__shfl_down(s2,off);
        }
        if(lane==0){red[wv][0]=s0;red[wv][1]=s1;red[wv][2]=s2;}
        __syncthreads();
        if(tid<3){
            float r=bo;
            #pragma unroll
            for(int w2=0;w2<8;++w2) r+=red[w2][tid];
            orow[t*3+tid]=r;
        }
    }
}

extern "C" void kernel_launch(void* const* d_in, const int* in_sizes, int n_in,
                              void* d_out, int out_size, void* d_ws, size_t ws_size,
                              hipStream_t stream) {
    const float* x     = (const float*)d_in[0];
    const float* W_x   = (const float*)d_in[1];
    const float* W_h   = (const float*)d_in[2];
    const float* b     = (const float*)d_in[3];
    const float* p_i   = (const float*)d_in[4];
    const float* p_f   = (const float*)d_in[5];
    const float* p_o   = (const float*)d_in[6];
    const float* W_out = (const float*)d_in[7];
    const float* b_out = (const float*)d_in[8];
    float* out = (float*)d_out;

    if (ws_size < WS_FULL) {
        lstm_fused_fb<<<BATCH, 512, 0, stream>>>(x, W_x, W_h, b, p_i, p_f, p_o,
                                                 W_out, b_out, out);
        return;
    }

    uint8_t* ws = (uint8_t*)d_ws;
    __hip_bfloat16* wbuf = (__hip_bfloat16*)(ws + WBUF_OFF);
    unsigned long long* hbuf = (unsigned long long*)(ws + HBUF_OFF);
    float* part = (float*)(ws + PART_OFF);

    hipMemsetAsync(hbuf, 0, HBUF_SZ, stream);    // kill stale tags (graph replay)
    reorder_w<<<(NBLK * UNITS * CPB + 255) / 256, 256, 0, stream>>>(W_h, wbuf);
    lstm_mb<<<NGRP * NBLK, 512, 0, stream>>>(x, W_x, b, p_i, p_f, p_o,
                                             W_out, wbuf, hbuf, part, out);
    finish_y<<<(BATCH * TLEN * 3 + 255) / 256, 256, 0, stream>>>(part, b_out, out);
}